// Round 5
// baseline (244.366 us; speedup 1.0000x reference)
//
#include <hip/hip_runtime.h>
#include <math.h>

// Problem constants
#define B_    8
#define L_    384
#define Q_    64
#define H_    256
#define R_    512          // B*Q rows
#define P_    73920        // L*(L+1)/2 pairs
#define NF4   18480        // P_/4 float4s per row
#define QF4   4620         // NF4/4 float4s per quarter-row block

// Workspace layout (float offsets). Total 1,444,864 floats = 5.78 MB.
#define WS_HIDT  0          // 8*256*384 : hidT[b][h][v]
#define WS_G     786432     // 512*512   : g[r][c*256+h]
#define WS_DOTC  1048576    // 512*2
#define WS_LOCS  1049600    // 512*2
#define WS_FACT  1050624    // 512*2
#define WS_EXEY  1051648    // 512*768   : per row: Ex[384], Ey_scaled[384]

// ---------------------------------------------------------------- K1: hidT transpose + qh->g->dotc->rowsmall
// grid = 224 x 512 threads:
//   [0,96)    : hidT tiles (8 b x 24 tiles, 2 tiles/block)
//   [96,224)  : qhg (128 blocks, 4 rows each)
__global__ __launch_bounds__(512) void k_f1(const float* __restrict__ hid,
                                            const float* __restrict__ Wv,
                                            const float* __restrict__ queries,
                                            const float* __restrict__ Wq,
                                            const float* __restrict__ bq_p,
                                            const float* __restrict__ bv,
                                            const float* __restrict__ qlocs,
                                            const float* __restrict__ qlogits,
                                            const float* __restrict__ Wc,
                                            const float* __restrict__ bc,
                                            const float* __restrict__ Wo,
                                            const float* __restrict__ bo,
                                            const float* __restrict__ Wf,
                                            const float* __restrict__ bf,
                                            float* __restrict__ ws,
                                            float* __restrict__ out) {
    __shared__ float smem[8320];    // 33.3 KB: 2x(64x65) transpose tiles OR q[4][256]+qh[4][512]
    int blk = blockIdx.x;
    int tid = threadIdx.x;

    if (blk < 96) {
        // hidT: in hid[b][v][h] (384x256), out hidT[b][h][v] (256x384). 2 tiles per block.
        int half = tid >> 8, lt = tid & 255;
        int b = blk / 12;
        int t2 = (blk % 12) * 2 + half;             // tile 0..23
        int mt = t2 % 6, nt = t2 / 6;               // M=384 (v), N=256 (h)
        float (*tt)[65] = (float(*)[65])(smem + half * 4160);
        int lane = lt & 63, row4 = lt >> 6;
        int m0 = mt * 64, n0 = nt * 64;
        const float* in = hid + b * 98304;
        float* op = ws + WS_HIDT + b * 98304;
#pragma unroll
        for (int p = 0; p < 16; p++)
            tt[p * 4 + row4][lane] = in[(m0 + p * 4 + row4) * 256 + n0 + lane];
        __syncthreads();
#pragma unroll
        for (int p = 0; p < 16; p++)
            op[(n0 + p * 4 + row4) * 384 + m0 + lane] = tt[lane][p * 4 + row4];
        return;
    }

    // ---- qhg: 4 rows per block
    float* q  = smem;          // [4][256]
    float* qh = smem + 1024;   // [4][512]
    int r0 = (blk - 96) * 4;

    for (int i = tid; i < 1024; i += 512)
        q[i] = queries[r0 * 256 + i];
    __syncthreads();

    // Phase A: qh[r][j] = q[r]@Wq[:,j] + bq[j]
    {
        int j = tid;
        float acc[4] = {0, 0, 0, 0};
        for (int h = 0; h < 256; h += 2) {
            float wa = Wq[h * 512 + j];
            float wb = Wq[(h + 1) * 512 + j];
#pragma unroll
            for (int r = 0; r < 4; r++)
                acc[r] += q[r * 256 + h] * wa + q[r * 256 + h + 1] * wb;
        }
        float bj = bq_p[j];
#pragma unroll
        for (int r = 0; r < 4; r++) qh[r * 512 + j] = acc[r] + bj;
    }
    __syncthreads();

    // Phase B: g[r][c*256+h] = sum_hin qh[r][c*256+hin] * Wv[h*512 + c*256 + hin]
    {
        int c = tid >> 8, h = tid & 255;
        const float4* wv4 = (const float4*)(Wv + h * 512 + c * 256);
        float acc[4] = {0, 0, 0, 0};
        for (int hp4 = 0; hp4 < 64; hp4++) {
            float4 w = wv4[hp4];
#pragma unroll
            for (int r = 0; r < 4; r++) {
                float4 qv = *reinterpret_cast<const float4*>(&qh[r * 512 + c * 256 + hp4 * 4]);
                acc[r] += qv.x * w.x + qv.y * w.y + qv.z * w.z + qv.w * w.w;
            }
        }
#pragma unroll
        for (int r = 0; r < 4; r++)
            ws[WS_G + (r0 + r) * 512 + tid] = acc[r];
    }

    // Phase C: dotc[r][c] = qh[r][c*256+:] . bv[c*256+:]  (wave w -> r=w>>1, c=w&1)
    {
        int w = tid >> 6, lane = tid & 63;
        int r = w >> 1, c = w & 1;
        float v = 0.f;
#pragma unroll
        for (int k = 0; k < 4; k++) {
            int h = lane + 64 * k;
            v += qh[r * 512 + c * 256 + h] * bv[c * 256 + h];
        }
#pragma unroll
        for (int off = 32; off; off >>= 1) v += __shfl_xor(v, off);
        if (lane == 0) ws[WS_DOTC + (r0 + r) * 2 + c] = v;
    }

    // Phase D: rowsmall, waves 0..3 -> row r0+w
    {
        int w = tid >> 6, lane = tid & 63;
        if (w < 4) {
            int r = r0 + w;
            float q0 = q[w * 256 + lane];
            float q1 = q[w * 256 + lane + 64];
            float q2 = q[w * 256 + lane + 128];
            float q3 = q[w * 256 + lane + 192];

            float x[10];
#pragma unroll
            for (int t = 0; t < 10; t++) {
                float v = q0 * Wc[lane * 10 + t] + q1 * Wc[(lane + 64) * 10 + t]
                        + q2 * Wc[(lane + 128) * 10 + t] + q3 * Wc[(lane + 192) * 10 + t];
#pragma unroll
                for (int off = 32; off; off >>= 1) v += __shfl_xor(v, off);
                x[t] = qlogits[r * 10 + t] + bc[t] + v;
            }
            float m = -1e30f;
#pragma unroll
            for (int t = 0; t < 10; t++) m = fmaxf(m, x[t]);
            float s = 0.f;
#pragma unroll
            for (int t = 0; t < 10; t++) { x[t] = expf(x[t] - m); s += x[t]; }
            float inv = 1.0f / s;
            if (lane == 0) {
#pragma unroll
                for (int t = 0; t < 10; t++) out[r * 10 + t] = x[t] * inv;
            }

#pragma unroll
            for (int k = 0; k < 2; k++) {
                float vo = q0 * Wo[lane * 2 + k] + q1 * Wo[(lane + 64) * 2 + k]
                         + q2 * Wo[(lane + 128) * 2 + k] + q3 * Wo[(lane + 192) * 2 + k];
                float vf = q0 * Wf[lane * 2 + k] + q1 * Wf[(lane + 64) * 2 + k]
                         + q2 * Wf[(lane + 128) * 2 + k] + q3 * Wf[(lane + 192) * 2 + k];
#pragma unroll
                for (int off = 32; off; off >>= 1) { vo += __shfl_xor(vo, off); vf += __shfl_xor(vf, off); }
                if (lane == 0) {
                    ws[WS_LOCS + r * 2 + k] = qlocs[r * 2 + k] + vo + bo[k];
                    float xx = vf + bf[k];
                    ws[WS_FACT + r * 2 + k] = (xx > 20.f) ? xx : log1pf(expf(xx));
                }
            }
        }
    }
}

// ---------------------------------------------------------------- K2: scores (float4, 4-way h-split) -> softmax prep
// block = 384 threads (6 waves), grid = 512 (one row each)
__global__ __launch_bounds__(384) void k_prep(const float* __restrict__ ws_c,
                                              float* __restrict__ ws,
                                              const int* __restrict__ mask) {
    __shared__ float g0[256], g1[256];
    __shared__ float part[4][96][8];
    __shared__ float s0[384], s1[384];
    __shared__ float Ex[384], Ey[384];
    __shared__ float scal[4];

    int tid = threadIdx.x;
    int r = blockIdx.x;                         // grid = 512
    int b = r >> 6;

    if (tid < 256) {
        g0[tid] = ws_c[WS_G + r * 512 + tid];
        g1[tid] = ws_c[WS_G + r * 512 + 256 + tid];
    }
    float dotc0 = ws_c[WS_DOTC + r * 2 + 0];
    float dotc1 = ws_c[WS_DOTC + r * 2 + 1];
    float lx = ws_c[WS_LOCS + r * 2 + 0], ly = ws_c[WS_LOCS + r * 2 + 1];
    float fx = ws_c[WS_FACT + r * 2 + 0], fy = ws_c[WS_FACT + r * 2 + 1];
    __syncthreads();

    // partial scores: thread = (hc, vg), hc = tid/96 over h-chunk of 64, vg -> v4 = vg*4
    const float* hT = ws_c + WS_HIDT + b * 98304;
    {
        int hc = tid / 96, vg = tid - hc * 96;
        const float* pb = hT + hc * 64 * 384 + vg * 4;
        float a0[4] = {0, 0, 0, 0}, a1[4] = {0, 0, 0, 0};
#pragma unroll 4
        for (int h = 0; h < 64; h++) {
            float4 x = *reinterpret_cast<const float4*>(pb + h * 384);
            float ga = g0[hc * 64 + h], gb = g1[hc * 64 + h];
            a0[0] += x.x * ga; a0[1] += x.y * ga; a0[2] += x.z * ga; a0[3] += x.w * ga;
            a1[0] += x.x * gb; a1[1] += x.y * gb; a1[2] += x.z * gb; a1[3] += x.w * gb;
        }
#pragma unroll
        for (int k = 0; k < 4; k++) {
            part[hc][vg][k]     = a0[k];
            part[hc][vg][4 + k] = a1[k];
        }
    }
    __syncthreads();

    // combine partials: v = tid
    float s0r, s1r;
    bool mk;
    {
        int vg = tid >> 2, k = tid & 3;
        float r0 = part[0][vg][k] + part[1][vg][k] + part[2][vg][k] + part[3][vg][k];
        float r1 = part[0][vg][4 + k] + part[1][vg][4 + k] + part[2][vg][4 + k] + part[3][vg][4 + k];
        mk = mask[b * 384 + tid] != 0;
        s0r = mk ? (r0 + dotc0) * 0.0625f : -1e8f;
        s1r = mk ? (r1 + dotc1) * 0.0625f : -1e8f;
        s0[tid] = s0r;
        s1[tid] = s1r;
    }
    __syncthreads();

    // wave 0: prefix-max of s0 -> m0, mM, m1
    if (tid < 64) {
        int l = tid;
        float p[6];
        p[0] = s0[l * 6 + 0];
#pragma unroll
        for (int k = 1; k < 6; k++) p[k] = fmaxf(p[k - 1], s0[l * 6 + k]);
        float run = p[5];
#pragma unroll
        for (int off = 1; off < 64; off <<= 1) {
            float t = __shfl_up(run, off);
            if (l >= off) run = fmaxf(run, t);
        }
        float excl = __shfl_up(run, 1);
        if (l == 0) excl = -1e30f;
        float m0 = __shfl(run, 63);
        float lm = -1e30f, lm1 = -1e30f;
#pragma unroll
        for (int k = 0; k < 6; k++) {
            float pm = fmaxf(excl, p[k]);
            float sv = s1[l * 6 + k];
            lm = fmaxf(lm, sv + pm);
            lm1 = fmaxf(lm1, sv);
        }
#pragma unroll
        for (int off = 1; off < 64; off <<= 1) {
            lm  = fmaxf(lm,  __shfl_xor(lm,  off));
            lm1 = fmaxf(lm1, __shfl_xor(lm1, off));
        }
        if (l == 0) { scal[0] = m0; scal[1] = lm1; scal[2] = lm; }
    }
    __syncthreads();

    // Ex, Ey elementwise (i = tid)
    float m0 = scal[0], m1 = scal[1], mM = scal[2];
    float exv, eyv;
    {
        float ds = (float)tid - lx;
        exv = expf(s0r - m0 - fx * ds * ds);
        float de = (float)tid - ly;
        eyv = mk ? expf(s1r - m1 - fy * de * de) : 0.f;
        Ex[tid] = exv;
        Ey[tid] = eyv;
    }
    __syncthreads();

    // wave 0: prefix-sum of Ex, S2, scale
    if (tid < 64) {
        int l = tid;
        float p[6];
        p[0] = Ex[l * 6 + 0];
#pragma unroll
        for (int k = 1; k < 6; k++) p[k] = p[k - 1] + Ex[l * 6 + k];
        float run = p[5];
#pragma unroll
        for (int off = 1; off < 64; off <<= 1) {
            float t = __shfl_up(run, off);
            if (l >= off) run += t;
        }
        float excl = __shfl_up(run, 1);
        if (l == 0) excl = 0.f;
        float s2l = 0.f;
#pragma unroll
        for (int k = 0; k < 6; k++)
            s2l += Ey[l * 6 + k] * (excl + p[k]);
#pragma unroll
        for (int off = 1; off < 64; off <<= 1) s2l += __shfl_xor(s2l, off);
        if (l == 0) {
            float C = expf(m0 + m1 - mM);
            scal[3] = C / (C * s2l + 1e-12f);
        }
    }
    __syncthreads();

    float scale = scal[3];
    float* exr = ws + WS_EXEY + r * 768;
    exr[tid]       = exv;
    exr[384 + tid] = eyv * scale;
}

// ---------------------------------------------------------------- K3: stream writes  out[p] = Ex[s]*Ey[e]
__global__ __launch_bounds__(256) void k_write(const float* __restrict__ ws,
                                               float* __restrict__ out) {
    __shared__ float exey[768];
    int tid = threadIdx.x;
    int r = blockIdx.x >> 2, q = blockIdx.x & 3;   // grid = 2048
    const float* exr = ws + WS_EXEY + r * 768;
    for (int i = tid; i < 768; i += 256) exey[i] = exr[i];
    __syncthreads();
    const float* Ex = exey;
    const float* Ey = exey + 384;

    float* ob = out + 5120 + r * 73920;
    int base = q * QF4;
    int end = base + QF4;
    for (int idx = base + tid; idx < end; idx += 256) {
        int p0 = idx << 2;
        int e = (int)((sqrtf(8.f * (float)p0 + 1.f) - 1.f) * 0.5f);
        int tri = (e * (e + 1)) >> 1;
        while (tri > p0) { e--; tri -= (e + 1); }
        while (p0 - tri > e) { tri += (e + 1); e++; }
        int s = p0 - tri;
        float ey = Ey[e];
        float4 v;
        v.x = Ex[s] * ey; if (++s > e) { s = 0; ey = Ey[++e]; }
        v.y = Ex[s] * ey; if (++s > e) { s = 0; ey = Ey[++e]; }
        v.z = Ex[s] * ey; if (++s > e) { s = 0; ey = Ey[++e]; }
        v.w = Ex[s] * ey;
        reinterpret_cast<float4*>(ob)[idx] = v;
    }
}

// ---------------------------------------------------------------- launch
extern "C" void kernel_launch(void* const* d_in, const int* in_sizes, int n_in,
                              void* d_out, int out_size, void* d_ws, size_t ws_size,
                              hipStream_t stream) {
    const float* hiddens = (const float*)d_in[0];
    const int* masks     = (const int*)d_in[1];   // jax bool -> int32 in harness
    const float* queries = (const float*)d_in[2];
    const float* qlocs   = (const float*)d_in[3];
    const float* qlogits = (const float*)d_in[4];
    const float* Wc = (const float*)d_in[5];
    const float* bc = (const float*)d_in[6];
    const float* Wq = (const float*)d_in[7];
    const float* bq = (const float*)d_in[8];
    const float* Wv = (const float*)d_in[9];
    const float* bv = (const float*)d_in[10];
    const float* Wo = (const float*)d_in[11];
    const float* bo = (const float*)d_in[12];
    const float* Wf = (const float*)d_in[13];
    const float* bf = (const float*)d_in[14];
    float* out = (float*)d_out;
    float* ws  = (float*)d_ws;     // needs 5.78 MB

    hipLaunchKernelGGL(k_f1,    dim3(224),  dim3(512), 0, stream,
                       hiddens, Wv, queries, Wq, bq, bv, qlocs, qlogits,
                       Wc, bc, Wo, bo, Wf, bf, ws, out);
    hipLaunchKernelGGL(k_prep,  dim3(512),  dim3(384), 0, stream, ws, ws, masks);
    hipLaunchKernelGGL(k_write, dim3(2048), dim3(256), 0, stream, ws, out);
}